// Round 1
// baseline (284.319 us; speedup 1.0000x reference)
//
#include <hip/hip_runtime.h>

#define L_DIM 128
#define B_DIM 128
#define D_DIM 1024
#define A_DIM 1024
#define H_DIM 2048

// ---------------------------------------------------------------------------
// K1: proj[b][a] = sum_d s_tm1[b][d] * W_sa[a][d]   (bias added later in K2)
// grid (16 a-tiles x 2 b-tiles x 16 k-chunks), 256 threads.
// 64x64 output tile per block, K-chunk = 64. Operands staged TRANSPOSED in
// LDS ([d][a] / [d][b], +4 pad) so compute reads are contiguous float4 per
// 16-lane group (conflict-free, 4-way same-address broadcast across wave).
// K-split partials combined via fp32 atomicAdd into zeroed ws buffer.
// ---------------------------------------------------------------------------
__global__ __launch_bounds__(256) void k1_gemm(const float* __restrict__ s_tm1,
                                               const float* __restrict__ W_sa,
                                               float* __restrict__ proj) {
    __shared__ float sWT[64][68];  // [d][a]
    __shared__ float sST[64][68];  // [d][b]
    const int a0 = blockIdx.x * 64;
    const int b0 = blockIdx.y * 64;
    const int k0 = blockIdx.z * 64;
    const int t  = threadIdx.x;

    // Stage + transpose: thread t handles float4 column c = t%16, row r = t/16 (+16p)
    {
        const int c = (t & 15) * 4;   // d offset within chunk
        const int r = t >> 4;         // row within tile
#pragma unroll
        for (int p = 0; p < 4; ++p) {
            const int row = r + p * 16;
            float4 w4 = *(const float4*)(W_sa + (size_t)(a0 + row) * D_DIM + k0 + c);
            sWT[c + 0][row] = w4.x; sWT[c + 1][row] = w4.y;
            sWT[c + 2][row] = w4.z; sWT[c + 3][row] = w4.w;
            float4 s4 = *(const float4*)(s_tm1 + (size_t)(b0 + row) * D_DIM + k0 + c);
            sST[c + 0][row] = s4.x; sST[c + 1][row] = s4.y;
            sST[c + 2][row] = s4.z; sST[c + 3][row] = s4.w;
        }
    }
    __syncthreads();

    const int tx = t & 15;   // a quad
    const int ty = t >> 4;   // b quad
    float acc[4][4] = {};
#pragma unroll 4
    for (int d = 0; d < 64; ++d) {
        float4 av = *(const float4*)&sWT[d][tx * 4];
        float4 bv = *(const float4*)&sST[d][ty * 4];
        float a_[4] = {av.x, av.y, av.z, av.w};
        float b_[4] = {bv.x, bv.y, bv.z, bv.w};
#pragma unroll
        for (int j = 0; j < 4; ++j)
#pragma unroll
            for (int i = 0; i < 4; ++i)
                acc[j][i] += a_[i] * b_[j];
    }

#pragma unroll
    for (int j = 0; j < 4; ++j)
#pragma unroll
        for (int i = 0; i < 4; ++i)
            atomicAdd(&proj[(size_t)(b0 + ty * 4 + j) * A_DIM + a0 + tx * 4 + i],
                      acc[j][i]);
}

// ---------------------------------------------------------------------------
// K2: e_raw[l][b] = exp( sum_a tanh(proj[b][a]+b_sa[a]+uh[l][b][a]) * w_a1[a]
//                        + b_a1 ) * mask[l][b]
// One wave per (l,b): wave reads the contiguous 4KB uh row as float4.
// ---------------------------------------------------------------------------
__device__ __forceinline__ float tanh_fast(float x) {
    float e = __expf(2.0f * x);                    // v_exp_f32 (scaled)
    return (e - 1.0f) * __builtin_amdgcn_rcpf(e + 1.0f);
}

__global__ __launch_bounds__(256) void k2_logits(const float* __restrict__ uh,
                                                 const float* __restrict__ proj,
                                                 const float* __restrict__ b_sa,
                                                 const float* __restrict__ w_a1,
                                                 const float* __restrict__ b_a1,
                                                 const float* __restrict__ mask,
                                                 float* __restrict__ e_raw) {
    const int wave = threadIdx.x >> 6;
    const int lane = threadIdx.x & 63;
    const int flat = blockIdx.x * 4 + wave;        // l*B + b, 0..16383
    const int b    = flat & (B_DIM - 1);

    const float* up = uh   + (size_t)flat * A_DIM;
    const float* pp = proj + (size_t)b    * A_DIM;

    float acc = 0.0f;
#pragma unroll
    for (int c = 0; c < 4; ++c) {
        const int off = c * 256 + lane * 4;
        float4 u = *(const float4*)(up + off);
        float4 p = *(const float4*)(pp + off);
        float4 s = *(const float4*)(b_sa + off);
        float4 w = *(const float4*)(w_a1 + off);
        acc += tanh_fast(u.x + p.x + s.x) * w.x;
        acc += tanh_fast(u.y + p.y + s.y) * w.y;
        acc += tanh_fast(u.z + p.z + s.z) * w.z;
        acc += tanh_fast(u.w + p.w + s.w) * w.w;
    }
#pragma unroll
    for (int off = 32; off > 0; off >>= 1)
        acc += __shfl_down(acc, off);
    if (lane == 0)
        e_raw[flat] = __expf(acc + b_a1[0]) * mask[flat];
}

// ---------------------------------------------------------------------------
// K3: normalize over L + attend[b][h] = sum_l e[l][b] * xs_h[l][b][h]
// grid (4 h-chunks x 128 b), 256 threads, float2 per thread (512 h / block).
// Chunk 0 also writes the normalized e_ij output.
// ---------------------------------------------------------------------------
__global__ __launch_bounds__(256) void k3_attend(const float* __restrict__ e_raw,
                                                 const float* __restrict__ xs_h,
                                                 float* __restrict__ out_e,
                                                 float* __restrict__ out_att) {
    __shared__ float se[L_DIM];
    __shared__ float s_inv;
    const int b     = blockIdx.y;
    const int chunk = blockIdx.x;
    const int t     = threadIdx.x;

    if (t < L_DIM) se[t] = e_raw[t * B_DIM + b];
    __syncthreads();
    if (t < 64) {
        float v = se[t] + se[t + 64];
#pragma unroll
        for (int off = 32; off > 0; off >>= 1)
            v += __shfl_down(v, off);
        if (t == 0) s_inv = 1.0f / v;
    }
    __syncthreads();
    if (t < L_DIM) se[t] *= s_inv;
    __syncthreads();
    if (chunk == 0 && t < L_DIM) out_e[t * B_DIM + b] = se[t];

    const int h0 = chunk * 512 + t * 2;
    const float* xp = xs_h + (size_t)b * H_DIM + h0;
    float accx = 0.0f, accy = 0.0f;
#pragma unroll 8
    for (int l = 0; l < L_DIM; ++l) {
        float  w = se[l];
        float2 x = *(const float2*)(xp + (size_t)l * (B_DIM * H_DIM));
        accx += w * x.x;
        accy += w * x.y;
    }
    float* op = out_att + (size_t)b * H_DIM + h0;
    op[0] = accx;
    op[1] = accy;
}

// ---------------------------------------------------------------------------
extern "C" void kernel_launch(void* const* d_in, const int* in_sizes, int n_in,
                              void* d_out, int out_size, void* d_ws, size_t ws_size,
                              hipStream_t stream) {
    const float* s_tm1 = (const float*)d_in[0];  // (B, D)
    const float* xs_h  = (const float*)d_in[1];  // (L, B, H)
    const float* uh    = (const float*)d_in[2];  // (L, B, A)
    const float* mask  = (const float*)d_in[3];  // (L, B)
    const float* W_sa  = (const float*)d_in[4];  // (A, D)
    const float* b_sa  = (const float*)d_in[5];  // (A,)
    const float* w_a1  = (const float*)d_in[6];  // (A,)
    const float* b_a1  = (const float*)d_in[7];  // scalar

    float* proj  = (float*)d_ws;                       // B*A floats
    float* e_raw = proj + (size_t)B_DIM * A_DIM;       // L*B floats

    float* out_e   = (float*)d_out;                    // (L, B) = 16384
    float* out_att = out_e + L_DIM * B_DIM;            // (B, H) = 262144

    // zero proj accumulator (graph-capture-safe)
    hipMemsetAsync(proj, 0, (size_t)B_DIM * A_DIM * sizeof(float), stream);

    k1_gemm<<<dim3(A_DIM / 64, B_DIM / 64, 16), 256, 0, stream>>>(s_tm1, W_sa, proj);
    k2_logits<<<dim3(L_DIM * B_DIM / 4), 256, 0, stream>>>(uh, proj, b_sa, w_a1,
                                                           b_a1, mask, e_raw);
    k3_attend<<<dim3(H_DIM / 512, B_DIM), 256, 0, stream>>>(e_raw, xs_h,
                                                            out_e, out_att);
}

// Round 2
// 256.683 us; speedup vs baseline: 1.1077x; 1.1077x over previous
//
#include <hip/hip_runtime.h>

#define L_DIM 128
#define B_DIM 128
#define D_DIM 1024
#define A_DIM 1024
#define H_DIM 2048
#define KSPLIT 16

// ---------------------------------------------------------------------------
// K1a: split-K GEMM partials. proj_part[kc][b][a] = sum_{d in chunk kc}
//      s_tm1[b][d] * W_sa[a][d].  No atomics: each (a-tile, b-tile, kc)
//      block owns its 64x64 tile of slice kc.  Partials land in L2 (8 MB).
// ---------------------------------------------------------------------------
__global__ __launch_bounds__(256) void k1_gemm_part(const float* __restrict__ s_tm1,
                                                    const float* __restrict__ W_sa,
                                                    float* __restrict__ proj_part) {
    __shared__ float sWT[64][68];  // [d][a], +4 pad
    __shared__ float sST[64][68];  // [d][b]
    const int a0 = blockIdx.x * 64;
    const int b0 = blockIdx.y * 64;
    const int kc = blockIdx.z;
    const int k0 = kc * 64;
    const int t  = threadIdx.x;

    {
        const int c = (t & 15) * 4;   // d offset within chunk
        const int r = t >> 4;
#pragma unroll
        for (int p = 0; p < 4; ++p) {
            const int row = r + p * 16;
            float4 w4 = *(const float4*)(W_sa + (size_t)(a0 + row) * D_DIM + k0 + c);
            sWT[c + 0][row] = w4.x; sWT[c + 1][row] = w4.y;
            sWT[c + 2][row] = w4.z; sWT[c + 3][row] = w4.w;
            float4 s4 = *(const float4*)(s_tm1 + (size_t)(b0 + row) * D_DIM + k0 + c);
            sST[c + 0][row] = s4.x; sST[c + 1][row] = s4.y;
            sST[c + 2][row] = s4.z; sST[c + 3][row] = s4.w;
        }
    }
    __syncthreads();

    const int tx = t & 15;   // a quad
    const int ty = t >> 4;   // b quad
    float acc[4][4] = {};
#pragma unroll 4
    for (int d = 0; d < 64; ++d) {
        float4 av = *(const float4*)&sWT[d][tx * 4];
        float4 bv = *(const float4*)&sST[d][ty * 4];
        float a_[4] = {av.x, av.y, av.z, av.w};
        float b_[4] = {bv.x, bv.y, bv.z, bv.w};
#pragma unroll
        for (int j = 0; j < 4; ++j)
#pragma unroll
            for (int i = 0; i < 4; ++i)
                acc[j][i] += a_[i] * b_[j];
    }

    float* base = proj_part + (size_t)kc * B_DIM * A_DIM;
#pragma unroll
    for (int j = 0; j < 4; ++j)
#pragma unroll
        for (int i = 0; i < 4; ++i)
            base[(size_t)(b0 + ty * 4 + j) * A_DIM + a0 + tx * 4 + i] = acc[j][i];
}

// ---------------------------------------------------------------------------
// K1b: proj = sum over the 16 K-slices. float4 per thread, fully coalesced.
// Reads 8 MB (L2-warm), writes 512 KB.
// ---------------------------------------------------------------------------
__global__ __launch_bounds__(256) void k1_reduce(const float* __restrict__ proj_part,
                                                 float* __restrict__ proj) {
    const size_t i4 = (size_t)blockIdx.x * 256 + threadIdx.x;  // float4 index
    const float4* pp = (const float4*)proj_part;
    float4 acc = pp[i4];
#pragma unroll
    for (int kc = 1; kc < KSPLIT; ++kc) {
        float4 v = pp[(size_t)kc * (B_DIM * A_DIM / 4) + i4];
        acc.x += v.x; acc.y += v.y; acc.z += v.z; acc.w += v.w;
    }
    ((float4*)proj)[i4] = acc;
}

// ---------------------------------------------------------------------------
// K2: e_raw[l][b] = exp( sum_a tanh(proj[b][a]+b_sa[a]+uh[l][b][a]) * w_a1[a]
//                        + b_a1 ) * mask[l][b].  One wave per (l,b).
// ---------------------------------------------------------------------------
__device__ __forceinline__ float tanh_fast(float x) {
    float e = __expf(2.0f * x);
    return (e - 1.0f) * __builtin_amdgcn_rcpf(e + 1.0f);
}

__global__ __launch_bounds__(256) void k2_logits(const float* __restrict__ uh,
                                                 const float* __restrict__ proj,
                                                 const float* __restrict__ b_sa,
                                                 const float* __restrict__ w_a1,
                                                 const float* __restrict__ b_a1,
                                                 const float* __restrict__ mask,
                                                 float* __restrict__ e_raw) {
    const int wave = threadIdx.x >> 6;
    const int lane = threadIdx.x & 63;
    const int flat = blockIdx.x * 4 + wave;        // l*B + b
    const int b    = flat & (B_DIM - 1);

    const float* up = uh   + (size_t)flat * A_DIM;
    const float* pp = proj + (size_t)b    * A_DIM;

    float acc = 0.0f;
#pragma unroll
    for (int c = 0; c < 4; ++c) {
        const int off = c * 256 + lane * 4;
        float4 u = *(const float4*)(up + off);
        float4 p = *(const float4*)(pp + off);
        float4 s = *(const float4*)(b_sa + off);
        float4 w = *(const float4*)(w_a1 + off);
        acc += tanh_fast(u.x + p.x + s.x) * w.x;
        acc += tanh_fast(u.y + p.y + s.y) * w.y;
        acc += tanh_fast(u.z + p.z + s.z) * w.z;
        acc += tanh_fast(u.w + p.w + s.w) * w.w;
    }
#pragma unroll
    for (int off = 32; off > 0; off >>= 1)
        acc += __shfl_down(acc, off);
    if (lane == 0)
        e_raw[flat] = __expf(acc + b_a1[0]) * mask[flat];
}

// ---------------------------------------------------------------------------
// K3: normalize over L + attend[b][h] = sum_l e[l][b] * xs_h[l][b][h]
// grid (4 h-chunks x 128 b), 256 threads, float2 per thread.
// ---------------------------------------------------------------------------
__global__ __launch_bounds__(256) void k3_attend(const float* __restrict__ e_raw,
                                                 const float* __restrict__ xs_h,
                                                 float* __restrict__ out_e,
                                                 float* __restrict__ out_att) {
    __shared__ float se[L_DIM];
    __shared__ float s_inv;
    const int b     = blockIdx.y;
    const int chunk = blockIdx.x;
    const int t     = threadIdx.x;

    if (t < L_DIM) se[t] = e_raw[t * B_DIM + b];
    __syncthreads();
    if (t < 64) {
        float v = se[t] + se[t + 64];
#pragma unroll
        for (int off = 32; off > 0; off >>= 1)
            v += __shfl_down(v, off);
        if (t == 0) s_inv = 1.0f / v;
    }
    __syncthreads();
    if (t < L_DIM) se[t] *= s_inv;
    __syncthreads();
    if (chunk == 0 && t < L_DIM) out_e[t * B_DIM + b] = se[t];

    const int h0 = chunk * 512 + t * 2;
    const float* xp = xs_h + (size_t)b * H_DIM + h0;
    float accx = 0.0f, accy = 0.0f;
#pragma unroll 8
    for (int l = 0; l < L_DIM; ++l) {
        float  w = se[l];
        float2 x = *(const float2*)(xp + (size_t)l * (B_DIM * H_DIM));
        accx += w * x.x;
        accy += w * x.y;
    }
    float* op = out_att + (size_t)b * H_DIM + h0;
    op[0] = accx;
    op[1] = accy;
}

// ---------------------------------------------------------------------------
extern "C" void kernel_launch(void* const* d_in, const int* in_sizes, int n_in,
                              void* d_out, int out_size, void* d_ws, size_t ws_size,
                              hipStream_t stream) {
    const float* s_tm1 = (const float*)d_in[0];  // (B, D)
    const float* xs_h  = (const float*)d_in[1];  // (L, B, H)
    const float* uh    = (const float*)d_in[2];  // (L, B, A)
    const float* mask  = (const float*)d_in[3];  // (L, B)
    const float* W_sa  = (const float*)d_in[4];  // (A, D)
    const float* b_sa  = (const float*)d_in[5];  // (A,)
    const float* w_a1  = (const float*)d_in[6];  // (A,)
    const float* b_a1  = (const float*)d_in[7];  // scalar

    float* proj_part = (float*)d_ws;                              // 16*B*A floats (8 MB)
    float* proj      = proj_part + (size_t)KSPLIT * B_DIM * A_DIM; // B*A floats
    float* e_raw     = proj + (size_t)B_DIM * A_DIM;              // L*B floats

    float* out_e   = (float*)d_out;                   // (L, B)
    float* out_att = out_e + L_DIM * B_DIM;           // (B, H)

    k1_gemm_part<<<dim3(A_DIM / 64, B_DIM / 64, KSPLIT), 256, 0, stream>>>(
        s_tm1, W_sa, proj_part);
    k1_reduce<<<dim3(B_DIM * A_DIM / 4 / 256), 256, 0, stream>>>(proj_part, proj);
    k2_logits<<<dim3(L_DIM * B_DIM / 4), 256, 0, stream>>>(uh, proj, b_sa, w_a1,
                                                           b_a1, mask, e_raw);
    k3_attend<<<dim3(H_DIM / 512, B_DIM), 256, 0, stream>>>(e_raw, xs_h,
                                                            out_e, out_att);
}